// Round 5
// baseline (122.632 us; speedup 1.0000x reference)
//
#include <hip/hip_runtime.h>

// Fused: bicubic 2x upsample -> leaky_relu(0.01) -> antialiased bicubic 2x down.
// NHWC f32, B=16, H=W=128, C=128.
// Round 5: lgkm-only barriers (prefetch/stores survive the barrier), 2 coarse
// rows per barrier-phase, period-3 register renaming (zero rotation movs),
// packed-f32 math, b128 LDS exchange.

typedef float f2 __attribute__((ext_vector_type(2)));

#define HH 128
#define WW 128
#define CC 128
#define RS 16       // output rows per strip
#define CH 16       // channels per block
#define PADF2 130   // LDS row stride in f2 (16B-aligned, conflict-free)

// lgkm-only barrier: keeps global loads/stores in flight across the sync.
#define LBAR() asm volatile("s_waitcnt lgkmcnt(0)\n\ts_barrier" ::: "memory")

__device__ __forceinline__ double keys_cubic(double x) {
  // JAX _fill_keys_cubic_kernel (a = -0.5)
  if (x >= 2.0) return 0.0;
  if (x >= 1.0) return ((-0.5 * x + 2.5) * x - 4.0) * x + 2.0;
  return (1.5 * x - 2.5) * x * x + 1.0;
}

__global__ __launch_bounds__(256) void fused_updown_kernel(
    const float* __restrict__ x, float* __restrict__ out) {
  __shared__ __align__(16) float wUpV[256][4];    // fine row/col -> 4 taps
  __shared__ __align__(16) float wDnE[4][8];      // out col 0,1,126,127 -> 8 taps
  __shared__ __align__(16) f2 rowv[2][CH][PADF2]; // packed (even,odd) fine rows

  const int tid = threadIdx.x;

  // ---- weight tables (renormalized truncation, matches jax.image.resize) ----
  {
    const int k = tid;
    const double q = 0.5 * k - 0.25;          // sample_f = (k+0.5)/2 - 0.5
    const int st = ((k + 1) >> 1) - 2;
    double wr[4], s = 0.0;
#pragma unroll
    for (int i = 0; i < 4; ++i) {
      const int col = st + i;
      double w = (col >= 0 && col <= 127) ? keys_cubic(fabs((double)col - q)) : 0.0;
      wr[i] = w; s += w;
    }
    const double inv = 1.0 / s;
#pragma unroll
    for (int i = 0; i < 4; ++i) wUpV[k][i] = (float)(wr[i] * inv);
  }
  if (tid < 4) {
    const int e = tid;
    const int j = (e < 2) ? e : 124 + e;      // 0,1,126,127
    const double p = 2.0 * j + 0.5;           // sample_f = (j+0.5)*2 - 0.5
    const int st = 2 * j - 3;
    double wr[8], s = 0.0;
#pragma unroll
    for (int i = 0; i < 8; ++i) {
      const int col = st + i;
      double w = (col >= 0 && col <= 255) ? keys_cubic(0.5 * fabs((double)col - p)) : 0.0;
      wr[i] = w; s += w;
    }
    const double inv = 1.0 / s;
#pragma unroll
    for (int i = 0; i < 8; ++i) wDnE[e][i] = (float)(wr[i] * inv);
  }
  __syncthreads();

  const int bid = blockIdx.x;
  const int b = bid & 15;
  const int strip = (bid >> 4) & 7;
  const int chunk = bid >> 7;
  const int oy0 = strip * RS;
  const int c0 = chunk * CH;
  const int c = tid & 15;                      // channel (lane-contiguous)
  const int g = tid >> 4;                      // col group 0..15
  const int col0 = g * 8;
  const bool gL = (g == 0), gR = (g == 15);

  const float* xbase = x + (size_t)b * (HH * WW * CC) + (size_t)col0 * CC + (c0 + c);
  float* obase = out + (size_t)b * (HH * WW * CC) + (size_t)col0 * CC + (c0 + c);
  const int m0 = oy0 - 2;

  auto load_row = [&](float (&d)[8], int row) {
    row = row < 0 ? 0 : (row > 127 ? 127 : row);
    const float* p = xbase + (size_t)row * (WW * CC);
#pragma unroll
    for (int j = 0; j < 8; ++j) d[j] = p[j * CC];
  };

  // vertical-downsample weight for output row oy at tap (interior const cst)
  auto wdGet = [&](int oy, float cst, int tap) -> float {
    if (oy < 0 || oy > 127) return 0.f;
    if (oy < 2) return wDnE[oy][tap];
    if (oy > 125) return wDnE[oy - 124][tap];
    return cst;
  };

// Horizontal pipeline for one staged packed fine-row pair in LDS slot SL,
// coarse row Mv; scatters into the 5 accumulator rows P0..P4 (rows Mv-2..Mv+2).
#define PROC(SL, Mv, P0, P1, P2, P3, P4) do {                                  \
    f2 vv[16];                                                                 \
    if (!gL) {                                                                 \
      *(float4*)&vv[0] = *(const float4*)&rowv[SL][c][col0 - 4];               \
      *(float4*)&vv[2] = *(const float4*)&rowv[SL][c][col0 - 2];               \
    } else {                                                                   \
      vv[0] = f2{0.f,0.f}; vv[1] = f2{0.f,0.f};                                \
      vv[2] = f2{0.f,0.f}; vv[3] = f2{0.f,0.f};                                \
    }                                                                          \
    *(float4*)&vv[4]  = *(const float4*)&rowv[SL][c][col0];                    \
    *(float4*)&vv[6]  = *(const float4*)&rowv[SL][c][col0 + 2];                \
    *(float4*)&vv[8]  = *(const float4*)&rowv[SL][c][col0 + 4];                \
    *(float4*)&vv[10] = *(const float4*)&rowv[SL][c][col0 + 6];                \
    if (!gR) {                                                                 \
      *(float4*)&vv[12] = *(const float4*)&rowv[SL][c][col0 + 8];              \
      *(float4*)&vv[14] = *(const float4*)&rowv[SL][c][col0 + 10];             \
    } else {                                                                   \
      vv[12] = f2{0.f,0.f}; vv[13] = f2{0.f,0.f};                              \
      vv[14] = f2{0.f,0.f}; vv[15] = f2{0.f,0.f};                              \
    }                                                                          \
    f2 ff[22];                                                                 \
    _Pragma("unroll") for (int u = 0; u < 22; ++u) {                           \
      const int s = (u >> 1) + 1;                                              \
      f2 t2;                                                                   \
      if (u & 1)                                                               \
        t2 = vv[s] * (-0.0234375f) + vv[s + 1] * 0.2265625f                    \
           + vv[s + 2] * 0.8671875f + vv[s + 3] * (-0.0703125f);               \
      else                                                                     \
        t2 = vv[s] * (-0.0703125f) + vv[s + 1] * 0.8671875f                    \
           + vv[s + 2] * 0.2265625f + vv[s + 3] * (-0.0234375f);               \
      ff[u] = __builtin_elementwise_max(t2, t2 * 0.01f);                       \
    }                                                                          \
    if (gL) {                                                                  \
      _Pragma("unroll") for (int u = 3; u <= 5; ++u) {                         \
        const int s = (u >> 1) + 1;                                            \
        const float4 w = *(const float4*)wUpV[u - 3];                          \
        f2 t2 = vv[s] * w.x + vv[s+1] * w.y + vv[s+2] * w.z + vv[s+3] * w.w;   \
        ff[u] = __builtin_elementwise_max(t2, t2 * 0.01f);                     \
      }                                                                        \
    }                                                                          \
    if (gR) {                                                                  \
      _Pragma("unroll") for (int u = 16; u <= 18; ++u) {                       \
        const int s = (u >> 1) + 1;                                            \
        const float4 w = *(const float4*)wUpV[237 + u];                        \
        f2 t2 = vv[s] * w.x + vv[s+1] * w.y + vv[s+2] * w.z + vv[s+3] * w.w;   \
        ff[u] = __builtin_elementwise_max(t2, t2 * 0.01f);                     \
      }                                                                        \
    }                                                                          \
    f2 tt[8];                                                                  \
    _Pragma("unroll") for (int jj = 0; jj < 8; ++jj) {                         \
      tt[jj] = (ff[2*jj]     + ff[2*jj + 7]) * (-0.01171875f)                  \
             + (ff[2*jj + 1] + ff[2*jj + 6]) * (-0.03515625f)                  \
             + (ff[2*jj + 2] + ff[2*jj + 5]) * 0.11328125f                     \
             + (ff[2*jj + 3] + ff[2*jj + 4]) * 0.43359375f;                    \
    }                                                                          \
    if (gL) {                                                                  \
      _Pragma("unroll") for (int jj = 0; jj < 2; ++jj) {                       \
        f2 s2 = f2{0.f, 0.f};                                                  \
        _Pragma("unroll") for (int i = 0; i < 8; ++i)                          \
          s2 += ff[2*jj + i] * wDnE[jj][i];                                    \
        tt[jj] = s2;                                                           \
      }                                                                        \
    }                                                                          \
    if (gR) {                                                                  \
      _Pragma("unroll") for (int jj = 6; jj < 8; ++jj) {                       \
        f2 s2 = f2{0.f, 0.f};                                                  \
        _Pragma("unroll") for (int i = 0; i < 8; ++i)                          \
          s2 += ff[2*jj + i] * wDnE[jj - 4][i];                                \
        tt[jj] = s2;                                                           \
      }                                                                        \
    }                                                                          \
    const float wE0 = wdGet((Mv) - 2, -0.01171875f, 7);                        \
    const float wE1 = wdGet((Mv) - 1, 0.11328125f, 5);                         \
    const float wE2 = wdGet((Mv),     0.43359375f, 3);                         \
    const float wE3 = wdGet((Mv) + 1, -0.03515625f, 1);                        \
    const float wO0 = wdGet((Mv) - 1, -0.03515625f, 6);                        \
    const float wO1 = wdGet((Mv),     0.43359375f, 4);                         \
    const float wO2 = wdGet((Mv) + 1, 0.11328125f, 2);                         \
    const float wO3 = wdGet((Mv) + 2, -0.01171875f, 0);                        \
    _Pragma("unroll") for (int jj = 0; jj < 8; ++jj) {                         \
      const float te = tt[jj].x, to = tt[jj].y;                                \
      P0[jj] = fmaf(wE0, te, P0[jj]);                                          \
      P1[jj] = fmaf(wE1, te, fmaf(wO0, to, P1[jj]));                           \
      P2[jj] = fmaf(wE2, te, fmaf(wO1, to, P2[jj]));                           \
      P3[jj] = fmaf(wE3, te, fmaf(wO2, to, P3[jj]));                           \
      P4[jj] = fmaf(wO3, to, P4[jj]);                                          \
    }                                                                          \
  } while (0)

// One pair-phase: steps tp=2P (coarse row mA) and tp+1 (mB).  At entry
// Ra..Rf = coarse rows mA-2..mA+3, Aa..Af = accs for out rows mA-2..mA+3.
// Loads next pair's rows into Ra,Rb (dead after v-ups); outputs+zeros Aa,Ab.
#define PAIR(P, Ra,Rb,Rc,Rd,Re,Rf, Aa,Ab,Ac,Ad,Ae,Af) do {                     \
    const int mA = m0 + 2*(P);                                                 \
    const int mB = mA + 1;                                                     \
    const bool mAok = (mA >= 0) && (mA <= 127);                                \
    const bool mBok = (mB >= 0) && (mB <= 127);                                \
    if (mAok) {                                                                \
      const float4 we = *(const float4*)wUpV[2 * mA];                          \
      const float4 wo = *(const float4*)wUpV[2 * mA + 1];                      \
      f2 vn[8];                                                                \
      _Pragma("unroll") for (int j = 0; j < 8; ++j) {                          \
        vn[j].x = fmaf(we.x, Ra[j], fmaf(we.y, Rb[j],                          \
                  fmaf(we.z, Rc[j], we.w * Rd[j])));                           \
        vn[j].y = fmaf(wo.x, Rb[j], fmaf(wo.y, Rc[j],                          \
                  fmaf(wo.z, Rd[j], wo.w * Re[j])));                           \
      }                                                                        \
      *(float4*)&rowv[0][c][col0]     = *(float4*)&vn[0];                      \
      *(float4*)&rowv[0][c][col0 + 2] = *(float4*)&vn[2];                      \
      *(float4*)&rowv[0][c][col0 + 4] = *(float4*)&vn[4];                      \
      *(float4*)&rowv[0][c][col0 + 6] = *(float4*)&vn[6];                      \
    }                                                                          \
    if (mBok) {                                                                \
      const float4 we = *(const float4*)wUpV[2 * mB];                          \
      const float4 wo = *(const float4*)wUpV[2 * mB + 1];                      \
      f2 vn[8];                                                                \
      _Pragma("unroll") for (int j = 0; j < 8; ++j) {                          \
        vn[j].x = fmaf(we.x, Rb[j], fmaf(we.y, Rc[j],                          \
                  fmaf(we.z, Rd[j], we.w * Re[j])));                           \
        vn[j].y = fmaf(wo.x, Rc[j], fmaf(wo.y, Rd[j],                          \
                  fmaf(wo.z, Re[j], wo.w * Rf[j])));                           \
      }                                                                        \
      *(float4*)&rowv[1][c][col0]     = *(float4*)&vn[0];                      \
      *(float4*)&rowv[1][c][col0 + 2] = *(float4*)&vn[2];                      \
      *(float4*)&rowv[1][c][col0 + 4] = *(float4*)&vn[4];                      \
      *(float4*)&rowv[1][c][col0 + 6] = *(float4*)&vn[6];                      \
    }                                                                          \
    load_row(Ra, mA + 4);                                                      \
    load_row(Rb, mA + 5);                                                      \
    LBAR();                                                                    \
    if (mAok) PROC(0, mA, Aa, Ab, Ac, Ad, Ae);                                 \
    if (mBok) PROC(1, mB, Ab, Ac, Ad, Ae, Af);                                 \
    if (mA - 2 >= oy0) {                                                       \
      float* op = obase + (size_t)(mA - 2) * (WW * CC);                        \
      _Pragma("unroll") for (int jj = 0; jj < 8; ++jj) op[jj * CC] = Aa[jj];   \
    }                                                                          \
    if (mB - 2 >= oy0) {                                                       \
      float* op = obase + (size_t)(mB - 2) * (WW * CC);                        \
      _Pragma("unroll") for (int jj = 0; jj < 8; ++jj) op[jj * CC] = Ab[jj];   \
    }                                                                          \
    _Pragma("unroll") for (int jj = 0; jj < 8; ++jj) { Aa[jj]=0.f; Ab[jj]=0.f; } \
    LBAR();                                                                    \
  } while (0)

  float r0[8], r1[8], r2[8], r3[8], r4[8], r5[8];
  float a0[8], a1[8], a2[8], a3[8], a4[8], a5[8];
#pragma unroll
  for (int i = 0; i < 8; ++i) {
    a0[i]=0.f; a1[i]=0.f; a2[i]=0.f; a3[i]=0.f; a4[i]=0.f; a5[i]=0.f;
  }
  load_row(r0, m0 - 2);
  load_row(r1, m0 - 1);
  load_row(r2, m0);
  load_row(r3, m0 + 1);
  load_row(r4, m0 + 2);
  load_row(r5, m0 + 3);

  for (int i = 0; i < 3; ++i) {
    const int p = 3 * i;
    PAIR(p,     r0,r1,r2,r3,r4,r5, a0,a1,a2,a3,a4,a5);
    PAIR(p + 1, r2,r3,r4,r5,r0,r1, a2,a3,a4,a5,a0,a1);
    PAIR(p + 2, r4,r5,r0,r1,r2,r3, a4,a5,a0,a1,a2,a3);
  }
  PAIR(9, r0,r1,r2,r3,r4,r5, a0,a1,a2,a3,a4,a5);

#undef PAIR
#undef PROC
}

extern "C" void kernel_launch(void* const* d_in, const int* in_sizes, int n_in,
                              void* d_out, int out_size, void* d_ws, size_t ws_size,
                              hipStream_t stream) {
  const float* x = (const float*)d_in[0];
  float* o = (float*)d_out;
  dim3 grid(16 * 8 * 8);   // batch(16) x strips(8) x channel-chunks(8)
  dim3 block(256);
  hipLaunchKernelGGL(fused_updown_kernel, grid, block, 0, stream, x, o);
}